// Round 1
// baseline (5962.760 us; speedup 1.0000x reference)
//
#include <hip/hip_runtime.h>

#define N_NODES  100000
#define N_EDGES  1600000
#define NF       128
#define N_GRAPHS 100

// ---------------------------------------------------------------- copy (agg = x)
__global__ __launch_bounds__(256) void copy_f4(const float4* __restrict__ src,
                                               float4* __restrict__ dst, int n4) {
    int i = blockIdx.x * 256 + threadIdx.x;
    if (i < n4) dst[i] = src[i];
}

// ---------------------------------------------------------------- edge scatter: agg[dst] += x[src]
// one thread per (edge, 4-feature chunk): 32 consecutive threads cover one edge's 128 feats
__global__ __launch_bounds__(256) void scatter_add(const float4* __restrict__ x,
                                                   const int* __restrict__ src,
                                                   const int* __restrict__ dst,
                                                   float* __restrict__ agg) {
    int idx = blockIdx.x * 256 + threadIdx.x;   // idx = e*32 + c
    int e = idx >> 5;
    int c = idx & 31;
    if (e >= N_EDGES) return;
    int s = src[e];
    int d = dst[e];
    float4 v = x[s * 32 + c];                   // coalesced 512B per 32 lanes
    float* p = agg + (size_t)d * NF + c * 4;
    atomicAdd(p + 0, v.x);
    atomicAdd(p + 1, v.y);
    atomicAdd(p + 2, v.z);
    atomicAdd(p + 3, v.w);
}

// ---------------------------------------------------------------- C[i][o] = relu(bias[o] + sum_k A[i][k]*W[o][k])
// Both A and W are indexed [row][k] row-major, so the inner loop reads BOTH
// operands along k as float4 — no LDS transpose anywhere.
// Block: 256 threads, 32 rows x 128 cols. Thread tile 4 rows x 4 cols
// (cols strided by 32 so w-reads are only 4-way bank conflicts; a-reads broadcast).
__global__ __launch_bounds__(256) void gemm_bias_relu(const float* __restrict__ A,
                                                      const float* __restrict__ W,
                                                      const float* __restrict__ bias,
                                                      float* __restrict__ C) {
    __shared__ float As[32][128];     // 16 KB, natural layout
    __shared__ float Ws[128][132];    // 67.6 KB, pad 4 keeps float4 alignment
    int tid  = threadIdx.x;
    int row0 = blockIdx.x * 32;

    const float4* A4 = (const float4*)(A + (size_t)row0 * NF);
    const float4* W4 = (const float4*)W;
    #pragma unroll
    for (int it = 0; it < 4; ++it) {            // stage A tile: 1024 float4
        int li = it * 256 + tid;
        int r = li >> 5, k4 = li & 31;
        *(float4*)&As[r][k4 * 4] = A4[r * 32 + k4];      // coalesced rd, conflict-free wr
    }
    #pragma unroll
    for (int it = 0; it < 16; ++it) {           // stage W: 4096 float4
        int li = it * 256 + tid;
        int o = li >> 5, k4 = li & 31;
        *(float4*)&Ws[o][k4 * 4] = W4[o * 32 + k4];
    }
    __syncthreads();

    int cg = tid & 31;          // col group: cols cg, cg+32, cg+64, cg+96
    int r0 = (tid >> 5) * 4;    // rows r0..r0+3
    float acc[4][4] = {};

    #pragma unroll 4
    for (int k4 = 0; k4 < 32; ++k4) {
        float4 a[4], w[4];
        #pragma unroll
        for (int i = 0; i < 4; ++i) a[i] = *(const float4*)&As[r0 + i][k4 * 4];
        #pragma unroll
        for (int j = 0; j < 4; ++j) w[j] = *(const float4*)&Ws[cg + 32 * j][k4 * 4];
        #pragma unroll
        for (int i = 0; i < 4; ++i)
            #pragma unroll
            for (int j = 0; j < 4; ++j)
                acc[i][j] += a[i].x * w[j].x + a[i].y * w[j].y +
                             a[i].z * w[j].z + a[i].w * w[j].w;
    }

    #pragma unroll
    for (int i = 0; i < 4; ++i) {
        size_t rowoff = (size_t)(row0 + r0 + i) * NF;
        #pragma unroll
        for (int j = 0; j < 4; ++j) {
            int c = cg + 32 * j;
            C[rowoff + c] = fmaxf(acc[i][j] + bias[c], 0.f);   // coalesced within wave
        }
    }
}

// ---------------------------------------------------------------- pooling: batch is SORTED
// 128 threads (one per feature), each block scans 256 consecutive nodes,
// flushing a partial sum with one atomic per (graph boundary, feature).
__global__ __launch_bounds__(128) void pool_sum(const float* __restrict__ h,
                                                const int* __restrict__ batch,
                                                float* __restrict__ sums,
                                                float* __restrict__ counts) {
    int f  = threadIdx.x;
    int n0 = blockIdx.x * 256;
    int n1 = min(n0 + 256, N_NODES);
    int cur = batch[n0];                 // broadcast load
    float acc = 0.f;
    for (int n = n0; n < n1; ++n) {
        int g = batch[n];
        if (g != cur) {                  // wave-uniform branch
            atomicAdd(&sums[cur * NF + f], acc);
            acc = 0.f; cur = g;
        }
        acc += h[(size_t)n * NF + f];
    }
    atomicAdd(&sums[cur * NF + f], acc);

    if (f == 0) {
        int cnt = 0; cur = batch[n0];
        for (int n = n0; n < n1; ++n) {
            int g = batch[n];
            if (g != cur) { atomicAdd(&counts[cur], (float)cnt); cnt = 0; cur = g; }
            ++cnt;
        }
        atomicAdd(&counts[cur], (float)cnt);
    }
}

__global__ __launch_bounds__(256) void pool_div(const float* __restrict__ sums,
                                                const float* __restrict__ counts,
                                                float* __restrict__ out) {
    int i = blockIdx.x * 256 + threadIdx.x;
    if (i < N_GRAPHS * NF) out[i] = sums[i] / fmaxf(counts[i >> 7], 1.f);
}

// ----------------------------------------------------------------
extern "C" void kernel_launch(void* const* d_in, const int* in_sizes, int n_in,
                              void* d_out, int out_size, void* d_ws, size_t ws_size,
                              hipStream_t stream) {
    const float* x     = (const float*)d_in[0];
    const int*   ei    = (const int*)d_in[1];     // (2, N_EDGES): row0=src, row1=dst
    const int*   batch = (const int*)d_in[2];
    const float* W1 = (const float*)d_in[3];  const float* b1 = (const float*)d_in[4];
    const float* W2 = (const float*)d_in[5];  const float* b2 = (const float*)d_in[6];
    const float* W3 = (const float*)d_in[7];  const float* b3 = (const float*)d_in[8];
    const float* W4 = (const float*)d_in[9];  const float* b4 = (const float*)d_in[10];
    const int* src = ei;
    const int* dst = ei + N_EDGES;

    float* out   = (float*)d_out;
    float* h_out = out + N_GRAPHS * NF;           // second tuple element, 100000x128

    // workspace: two 51.2MB ping-pong buffers + pool scratch (needs ~102.5 MB)
    float* bufA = (float*)d_ws;
    float* bufB = bufA + (size_t)N_NODES * NF;
    float* sums = bufB + (size_t)N_NODES * NF;
    float* cnts = sums + N_GRAPHS * NF;

    const int n4 = N_NODES * NF / 4;              // 3.2M float4 -> 12500 blocks
    const int scatter_blocks = N_EDGES * 32 / 256; // 200000

    hipMemsetAsync(sums, 0, (N_GRAPHS * NF + N_GRAPHS) * sizeof(float), stream);

    // layer group 1: agg1 = x + scatter(x); h1 = mlp1(agg1)
    copy_f4<<<n4 / 256, 256, 0, stream>>>((const float4*)x, (float4*)bufA, n4);
    scatter_add<<<scatter_blocks, 256, 0, stream>>>((const float4*)x, src, dst, bufA);
    gemm_bias_relu<<<N_NODES / 32, 256, 0, stream>>>(bufA, W1, b1, bufB);
    gemm_bias_relu<<<N_NODES / 32, 256, 0, stream>>>(bufB, W2, b2, bufA);   // h1 -> bufA

    // layer group 2: agg2 = h1 + scatter(h1); h = mlp2(agg2)
    copy_f4<<<n4 / 256, 256, 0, stream>>>((const float4*)bufA, (float4*)bufB, n4);
    scatter_add<<<scatter_blocks, 256, 0, stream>>>((const float4*)bufA, src, dst, bufB);
    gemm_bias_relu<<<N_NODES / 32, 256, 0, stream>>>(bufB, W3, b3, bufA);
    gemm_bias_relu<<<N_NODES / 32, 256, 0, stream>>>(bufA, W4, b4, h_out);  // h -> out

    // global mean pool
    pool_sum<<<(N_NODES + 255) / 256, 128, 0, stream>>>(h_out, batch, sums, cnts);
    pool_div<<<(N_GRAPHS * NF + 255) / 256, 256, 0, stream>>>(sums, cnts, out);
}

// Round 2
// 1005.516 us; speedup vs baseline: 5.9300x; 5.9300x over previous
//
#include <hip/hip_runtime.h>

#define N_NODES  100000
#define N_EDGES  1600000
#define NF       128
#define N_GRAPHS 100
#define NB_SCAN  98          // ceil(100000 / 1024)

// ---------------------------------------------------------------- CSR build
__global__ __launch_bounds__(256) void hist(const int* __restrict__ dst,
                                            int* __restrict__ deg) {
    int e = blockIdx.x * 256 + threadIdx.x;
    if (e < N_EDGES) atomicAdd(&deg[dst[e]], 1);
}

// block scans 1024 elements (4/thread), writes exclusive scan + block sum
__global__ __launch_bounds__(256) void scan_local(const int* __restrict__ deg,
                                                  int* __restrict__ rowptr,
                                                  int* __restrict__ bsum) {
    __shared__ int s[256];
    int t = threadIdx.x;
    int base = blockIdx.x * 1024 + t * 4;
    int v[4], sum = 0;
    #pragma unroll
    for (int i = 0; i < 4; ++i) {
        v[i] = (base + i < N_NODES) ? deg[base + i] : 0;
        sum += v[i];
    }
    s[t] = sum;
    __syncthreads();
    for (int off = 1; off < 256; off <<= 1) {       // Hillis-Steele inclusive
        int x = (t >= off) ? s[t - off] : 0;
        __syncthreads();
        s[t] += x;
        __syncthreads();
    }
    int excl = s[t] - sum;
    #pragma unroll
    for (int i = 0; i < 4; ++i) {
        if (base + i < N_NODES) rowptr[base + i] = excl;
        excl += v[i];
    }
    if (t == 255) bsum[blockIdx.x] = s[255];
}

__global__ __launch_bounds__(128) void scan_block(int* __restrict__ bsum, int nb) {
    __shared__ int s[128];
    int t = threadIdx.x;
    int v = (t < nb) ? bsum[t] : 0;
    s[t] = v;
    __syncthreads();
    for (int off = 1; off < 128; off <<= 1) {
        int x = (t >= off) ? s[t - off] : 0;
        __syncthreads();
        s[t] += x;
        __syncthreads();
    }
    if (t < nb) bsum[t] = s[t] - v;                 // exclusive
}

__global__ __launch_bounds__(256) void scan_add(int* __restrict__ rowptr,
                                                const int* __restrict__ bsum) {
    int i = blockIdx.x * 256 + threadIdx.x;
    if (i < N_NODES) rowptr[i] += bsum[i >> 10];
    if (i == 0) rowptr[N_NODES] = N_EDGES;
}

// cur[] must be zeroed; pos within bucket unordered (sum is order-free)
__global__ __launch_bounds__(256) void fill_csr(const int* __restrict__ src,
                                                const int* __restrict__ dst,
                                                const int* __restrict__ rowptr,
                                                int* __restrict__ cur,
                                                int* __restrict__ csr) {
    int e = blockIdx.x * 256 + threadIdx.x;
    if (e < N_EDGES) {
        int d = dst[e];
        int pos = rowptr[d] + atomicAdd(&cur[d], 1);
        csr[pos] = src[e];
    }
}

// ---------------------------------------------------------------- gather: out[n] = x[n] + sum_{e in N(n)} x[csr[e]]
// 32 threads per node, one float4 chunk each; csr[e] broadcasts within the node's lanes
__global__ __launch_bounds__(256) void gather_agg(const float4* __restrict__ x,
                                                  const int* __restrict__ rowptr,
                                                  const int* __restrict__ csr,
                                                  float4* __restrict__ out) {
    int idx = blockIdx.x * 256 + threadIdx.x;
    int node = idx >> 5, c = idx & 31;
    int beg = rowptr[node], end = rowptr[node + 1];
    float4 acc = x[node * 32 + c];                  // self term (fuses the old copy)
    for (int e = beg; e < end; ++e) {
        int s = csr[e];
        float4 v = x[s * 32 + c];                   // 512B coalesced segment per node
        acc.x += v.x; acc.y += v.y; acc.z += v.z; acc.w += v.w;
    }
    out[node * 32 + c] = acc;
}

// ---------------------------------------------------------------- C[i][o] = relu(bias[o] + sum_k A[i][k]*W[o][k])
__global__ __launch_bounds__(256) void gemm_bias_relu(const float* __restrict__ A,
                                                      const float* __restrict__ W,
                                                      const float* __restrict__ bias,
                                                      float* __restrict__ C) {
    __shared__ float As[32][128];
    __shared__ float Ws[128][132];
    int tid  = threadIdx.x;
    int row0 = blockIdx.x * 32;

    const float4* A4 = (const float4*)(A + (size_t)row0 * NF);
    const float4* W4 = (const float4*)W;
    #pragma unroll
    for (int it = 0; it < 4; ++it) {
        int li = it * 256 + tid;
        int r = li >> 5, k4 = li & 31;
        *(float4*)&As[r][k4 * 4] = A4[r * 32 + k4];
    }
    #pragma unroll
    for (int it = 0; it < 16; ++it) {
        int li = it * 256 + tid;
        int o = li >> 5, k4 = li & 31;
        *(float4*)&Ws[o][k4 * 4] = W4[o * 32 + k4];
    }
    __syncthreads();

    int cg = tid & 31;
    int r0 = (tid >> 5) * 4;
    float acc[4][4] = {};

    #pragma unroll 4
    for (int k4 = 0; k4 < 32; ++k4) {
        float4 a[4], w[4];
        #pragma unroll
        for (int i = 0; i < 4; ++i) a[i] = *(const float4*)&As[r0 + i][k4 * 4];
        #pragma unroll
        for (int j = 0; j < 4; ++j) w[j] = *(const float4*)&Ws[cg + 32 * j][k4 * 4];
        #pragma unroll
        for (int i = 0; i < 4; ++i)
            #pragma unroll
            for (int j = 0; j < 4; ++j)
                acc[i][j] += a[i].x * w[j].x + a[i].y * w[j].y +
                             a[i].z * w[j].z + a[i].w * w[j].w;
    }

    #pragma unroll
    for (int i = 0; i < 4; ++i) {
        size_t rowoff = (size_t)(row0 + r0 + i) * NF;
        #pragma unroll
        for (int j = 0; j < 4; ++j) {
            int c = cg + 32 * j;
            C[rowoff + c] = fmaxf(acc[i][j] + bias[c], 0.f);
        }
    }
}

// ---------------------------------------------------------------- pooling (batch sorted)
__global__ __launch_bounds__(128) void pool_sum(const float* __restrict__ h,
                                                const int* __restrict__ batch,
                                                float* __restrict__ sums,
                                                float* __restrict__ counts) {
    int f  = threadIdx.x;
    int n0 = blockIdx.x * 256;
    int n1 = min(n0 + 256, N_NODES);
    int cur = batch[n0];
    float acc = 0.f;
    for (int n = n0; n < n1; ++n) {
        int g = batch[n];
        if (g != cur) {
            atomicAdd(&sums[cur * NF + f], acc);
            acc = 0.f; cur = g;
        }
        acc += h[(size_t)n * NF + f];
    }
    atomicAdd(&sums[cur * NF + f], acc);

    if (f == 0) {
        int cnt = 0; cur = batch[n0];
        for (int n = n0; n < n1; ++n) {
            int g = batch[n];
            if (g != cur) { atomicAdd(&counts[cur], (float)cnt); cnt = 0; cur = g; }
            ++cnt;
        }
        atomicAdd(&counts[cur], (float)cnt);
    }
}

__global__ __launch_bounds__(256) void pool_div(const float* __restrict__ sums,
                                                const float* __restrict__ counts,
                                                float* __restrict__ out) {
    int i = blockIdx.x * 256 + threadIdx.x;
    if (i < N_GRAPHS * NF) out[i] = sums[i] / fmaxf(counts[i >> 7], 1.f);
}

// ----------------------------------------------------------------
extern "C" void kernel_launch(void* const* d_in, const int* in_sizes, int n_in,
                              void* d_out, int out_size, void* d_ws, size_t ws_size,
                              hipStream_t stream) {
    const float* x     = (const float*)d_in[0];
    const int*   ei    = (const int*)d_in[1];
    const int*   batch = (const int*)d_in[2];
    const float* W1 = (const float*)d_in[3];  const float* b1 = (const float*)d_in[4];
    const float* W2 = (const float*)d_in[5];  const float* b2 = (const float*)d_in[6];
    const float* W3 = (const float*)d_in[7];  const float* b3 = (const float*)d_in[8];
    const float* W4 = (const float*)d_in[9];  const float* b4 = (const float*)d_in[10];
    const int* src = ei;
    const int* dst = ei + N_EDGES;

    float* out   = (float*)d_out;
    float* h_out = out + N_GRAPHS * NF;            // 100000x128 — doubles as ping-pong buf

    // workspace (~59 MB): one 51.2MB buffer + CSR + small arrays
    float* bufA   = (float*)d_ws;
    int*   rowptr = (int*)(bufA + (size_t)N_NODES * NF);   // N_NODES+1
    int*   deg    = rowptr + N_NODES + 1;                  // N_NODES (also cursor)
    int*   bsum   = deg + N_NODES;                         // 128
    int*   csr    = bsum + 128;                            // N_EDGES
    float* sums   = (float*)(csr + N_EDGES);               // N_GRAPHS*NF
    float* cnts   = sums + N_GRAPHS * NF;                  // N_GRAPHS

    const int edge_blocks = N_EDGES / 256;         // 6250
    const int gather_blocks = N_NODES * 32 / 256;  // 12500

    // ---- CSR build (once; edge_index identical for both aggregations)
    hipMemsetAsync(deg, 0, N_NODES * sizeof(int), stream);
    hipMemsetAsync(sums, 0, (N_GRAPHS * NF + N_GRAPHS) * sizeof(float), stream);
    hist<<<edge_blocks, 256, 0, stream>>>(dst, deg);
    scan_local<<<NB_SCAN, 256, 0, stream>>>(deg, rowptr, bsum);
    scan_block<<<1, 128, 0, stream>>>(bsum, NB_SCAN);
    scan_add<<<(N_NODES + 256) / 256, 256, 0, stream>>>(rowptr, bsum);
    hipMemsetAsync(deg, 0, N_NODES * sizeof(int), stream);
    fill_csr<<<edge_blocks, 256, 0, stream>>>(src, dst, rowptr, deg, csr);

    // ---- layer group 1
    gather_agg<<<gather_blocks, 256, 0, stream>>>((const float4*)x, rowptr, csr, (float4*)bufA);
    gemm_bias_relu<<<N_NODES / 32, 256, 0, stream>>>(bufA, W1, b1, h_out);
    gemm_bias_relu<<<N_NODES / 32, 256, 0, stream>>>(h_out, W2, b2, bufA);    // h1 -> bufA

    // ---- layer group 2
    gather_agg<<<gather_blocks, 256, 0, stream>>>((const float4*)bufA, rowptr, csr, (float4*)h_out);
    gemm_bias_relu<<<N_NODES / 32, 256, 0, stream>>>(h_out, W3, b3, bufA);
    gemm_bias_relu<<<N_NODES / 32, 256, 0, stream>>>(bufA, W4, b4, h_out);    // h -> out

    // ---- global mean pool
    pool_sum<<<(N_NODES + 255) / 256, 128, 0, stream>>>(h_out, batch, sums, cnts);
    pool_div<<<(N_GRAPHS * NF + 255) / 256, 256, 0, stream>>>(sums, cnts, out);
}

// Round 3
// 629.669 us; speedup vs baseline: 9.4697x; 1.5969x over previous
//
#include <hip/hip_runtime.h>

#define N_NODES  100000
#define N_EDGES  1600000
#define NF       128
#define N_GRAPHS 100
#define NB_SCAN  98          // ceil(100000 / 1024)

typedef __attribute__((ext_vector_type(8))) short bf16x8;
typedef __attribute__((ext_vector_type(4))) float f32x4;
typedef unsigned int uint32;
typedef unsigned short ushort16;

// ---------------------------------------------------------------- bf16 helpers (RNE)
__device__ __forceinline__ unsigned short f2bf(float f) {
    union { float f; uint32 u; } x; x.f = f;
    return (unsigned short)((x.u + 0x7fffu + ((x.u >> 16) & 1u)) >> 16);
}
__device__ __forceinline__ uint32 pack2bf(float a, float b) {
    union { float f; uint32 u; } x, y; x.f = a; y.f = b;
    uint32 lo = (x.u + 0x7fffu + ((x.u >> 16) & 1u)) >> 16;
    uint32 hi = (y.u + 0x7fffu + ((y.u >> 16) & 1u)) & 0xffff0000u;
    return lo | hi;
}

// ---------------------------------------------------------------- fp32 -> bf16 convert (8 elems/thread)
__global__ __launch_bounds__(256) void conv_bf16(const float4* __restrict__ in,
                                                 uint4* __restrict__ out, int n8) {
    int i = blockIdx.x * 256 + threadIdx.x;
    if (i >= n8) return;
    float4 a = in[i * 2], b = in[i * 2 + 1];
    uint4 o;
    o.x = pack2bf(a.x, a.y); o.y = pack2bf(a.z, a.w);
    o.z = pack2bf(b.x, b.y); o.w = pack2bf(b.z, b.w);
    out[i] = o;
}

// ---------------------------------------------------------------- CSR build
__global__ __launch_bounds__(256) void hist(const int* __restrict__ dst,
                                            int* __restrict__ deg) {
    int e = blockIdx.x * 256 + threadIdx.x;
    if (e < N_EDGES) atomicAdd(&deg[dst[e]], 1);
}

__global__ __launch_bounds__(256) void scan_local(const int* __restrict__ deg,
                                                  int* __restrict__ rowptr,
                                                  int* __restrict__ bsum) {
    __shared__ int s[256];
    int t = threadIdx.x;
    int base = blockIdx.x * 1024 + t * 4;
    int v[4], sum = 0;
    #pragma unroll
    for (int i = 0; i < 4; ++i) {
        v[i] = (base + i < N_NODES) ? deg[base + i] : 0;
        sum += v[i];
    }
    s[t] = sum;
    __syncthreads();
    for (int off = 1; off < 256; off <<= 1) {
        int x = (t >= off) ? s[t - off] : 0;
        __syncthreads();
        s[t] += x;
        __syncthreads();
    }
    int excl = s[t] - sum;
    #pragma unroll
    for (int i = 0; i < 4; ++i) {
        if (base + i < N_NODES) rowptr[base + i] = excl;
        excl += v[i];
    }
    if (t == 255) bsum[blockIdx.x] = s[255];
}

__global__ __launch_bounds__(128) void scan_block(int* __restrict__ bsum, int nb) {
    __shared__ int s[128];
    int t = threadIdx.x;
    int v = (t < nb) ? bsum[t] : 0;
    s[t] = v;
    __syncthreads();
    for (int off = 1; off < 128; off <<= 1) {
        int x = (t >= off) ? s[t - off] : 0;
        __syncthreads();
        s[t] += x;
        __syncthreads();
    }
    if (t < nb) bsum[t] = s[t] - v;
}

__global__ __launch_bounds__(256) void scan_add(int* __restrict__ rowptr,
                                                const int* __restrict__ bsum) {
    int i = blockIdx.x * 256 + threadIdx.x;
    if (i < N_NODES) rowptr[i] += bsum[i >> 10];
    if (i == 0) rowptr[N_NODES] = N_EDGES;
}

__global__ __launch_bounds__(256) void fill_csr(const int* __restrict__ src,
                                                const int* __restrict__ dst,
                                                const int* __restrict__ rowptr,
                                                int* __restrict__ cur,
                                                int* __restrict__ csr) {
    int e = blockIdx.x * 256 + threadIdx.x;
    if (e < N_EDGES) {
        int d = dst[e];
        int pos = rowptr[d] + atomicAdd(&cur[d], 1);
        csr[pos] = src[e];
    }
}

// ---------------------------------------------------------------- bf16 gather: out[n] = x[n] + sum x[csr[e]]
// 16 lanes per node, each lane owns one 16B chunk (8 bf16); fp32 accumulation
__global__ __launch_bounds__(256) void gather_agg_bf16(const uint4* __restrict__ x,
                                                       const int* __restrict__ rowptr,
                                                       const int* __restrict__ csr,
                                                       uint4* __restrict__ out) {
    int idx = blockIdx.x * 256 + threadIdx.x;
    int node = idx >> 4, c = idx & 15;
    int beg = rowptr[node], end = rowptr[node + 1];

    float acc[8];
    {
        uint4 v = x[node * 16 + c];
        uint32 u[4] = {v.x, v.y, v.z, v.w};
        #pragma unroll
        for (int i = 0; i < 4; ++i) {
            union { uint32 b; float f; } lo, hi;
            lo.b = u[i] << 16; hi.b = u[i] & 0xffff0000u;
            acc[2 * i] = lo.f; acc[2 * i + 1] = hi.f;
        }
    }
    for (int e = beg; e < end; ++e) {
        int s = csr[e];
        uint4 v = x[s * 16 + c];               // 256B coalesced per node group
        uint32 u[4] = {v.x, v.y, v.z, v.w};
        #pragma unroll
        for (int i = 0; i < 4; ++i) {
            union { uint32 b; float f; } lo, hi;
            lo.b = u[i] << 16; hi.b = u[i] & 0xffff0000u;
            acc[2 * i] += lo.f; acc[2 * i + 1] += hi.f;
        }
    }
    uint4 o;
    o.x = pack2bf(acc[0], acc[1]); o.y = pack2bf(acc[2], acc[3]);
    o.z = pack2bf(acc[4], acc[5]); o.w = pack2bf(acc[6], acc[7]);
    out[node * 16 + c] = o;
}

// ---------------------------------------------------------------- MFMA GEMM: C = relu(A @ W^T + bias)
// A [M x 128] bf16 row-major; W [128 x 128] bf16 row-major over k (i.e. B^T layout).
// Block: 256 thr = 4 waves, 128 rows x 128 cols. Wave: 2 row-tiles x 8 col-tiles,
// K=128 in 4 MFMA steps. A/B frag: lane reads 8 contiguous k at row (lane&15),
// k-off quad*8 -> one ds_read_b128. C/D: col=lane&15, row=quad*4+reg.
template <bool F32OUT>
__global__ __launch_bounds__(256) void gemm_mfma(const unsigned short* __restrict__ A,
                                                 const unsigned short* __restrict__ W,
                                                 const float* __restrict__ bias,
                                                 void* __restrict__ Cout, int M) {
    __shared__ unsigned short As[128 * 136];   // +8 pad keeps 16B align, staggers banks
    __shared__ unsigned short Ws[128 * 136];
    __shared__ float bs[128];
    int tid  = threadIdx.x;
    int row0 = blockIdx.x * 128;

    #pragma unroll
    for (int it = 0; it < 8; ++it) {           // stage A: 128 rows x 256 B
        int li = it * 256 + tid;
        int r = li >> 4, s = li & 15;
        uint4 v = make_uint4(0u, 0u, 0u, 0u);
        if (row0 + r < M) v = *(const uint4*)(A + (size_t)(row0 + r) * NF + s * 8);
        *(uint4*)&As[r * 136 + s * 8] = v;
    }
    #pragma unroll
    for (int it = 0; it < 8; ++it) {           // stage W: 32 KB
        int li = it * 256 + tid;
        int r = li >> 4, s = li & 15;
        *(uint4*)&Ws[r * 136 + s * 8] = *(const uint4*)(W + r * NF + s * 8);
    }
    if (tid < 128) bs[tid] = bias[tid];
    __syncthreads();

    int wv = tid >> 6;         // wave 0..3 -> rows wv*32..wv*32+31
    int l  = tid & 63;
    int lm = l & 15;
    int q  = l >> 4;

    f32x4 acc[2][8];
    #pragma unroll
    for (int i = 0; i < 2; ++i)
        #pragma unroll
        for (int j = 0; j < 8; ++j) acc[i][j] = (f32x4){0.f, 0.f, 0.f, 0.f};

    #pragma unroll
    for (int ks = 0; ks < 4; ++ks) {
        int ko = ks * 32 + q * 8;
        bf16x8 a0 = *(const bf16x8*)&As[(wv * 32 + lm) * 136 + ko];
        bf16x8 a1 = *(const bf16x8*)&As[(wv * 32 + 16 + lm) * 136 + ko];
        #pragma unroll
        for (int ct = 0; ct < 8; ++ct) {
            bf16x8 b = *(const bf16x8*)&Ws[(ct * 16 + lm) * 136 + ko];
            acc[0][ct] = __builtin_amdgcn_mfma_f32_16x16x32_bf16(a0, b, acc[0][ct], 0, 0, 0);
            acc[1][ct] = __builtin_amdgcn_mfma_f32_16x16x32_bf16(a1, b, acc[1][ct], 0, 0, 0);
        }
    }

    #pragma unroll
    for (int rt = 0; rt < 2; ++rt) {
        #pragma unroll
        for (int ct = 0; ct < 8; ++ct) {
            int col = ct * 16 + lm;
            float bv = bs[col];
            #pragma unroll
            for (int r = 0; r < 4; ++r) {
                int row = row0 + wv * 32 + rt * 16 + q * 4 + r;
                if (row < M) {
                    float v = fmaxf(acc[rt][ct][r] + bv, 0.f);
                    if (F32OUT) ((float*)Cout)[(size_t)row * NF + col] = v;
                    else ((unsigned short*)Cout)[(size_t)row * NF + col] = f2bf(v);
                }
            }
        }
    }
}

// ---------------------------------------------------------------- pooling (batch sorted)
__global__ __launch_bounds__(128) void pool_sum(const float* __restrict__ h,
                                                const int* __restrict__ batch,
                                                float* __restrict__ sums,
                                                float* __restrict__ counts) {
    int f  = threadIdx.x;
    int n0 = blockIdx.x * 256;
    int n1 = min(n0 + 256, N_NODES);
    int cur = batch[n0];
    float acc = 0.f;
    for (int n = n0; n < n1; ++n) {
        int g = batch[n];
        if (g != cur) {
            atomicAdd(&sums[cur * NF + f], acc);
            acc = 0.f; cur = g;
        }
        acc += h[(size_t)n * NF + f];
    }
    atomicAdd(&sums[cur * NF + f], acc);

    if (f == 0) {
        int cnt = 0; cur = batch[n0];
        for (int n = n0; n < n1; ++n) {
            int g = batch[n];
            if (g != cur) { atomicAdd(&counts[cur], (float)cnt); cnt = 0; cur = g; }
            ++cnt;
        }
        atomicAdd(&counts[cur], (float)cnt);
    }
}

__global__ __launch_bounds__(256) void pool_div(const float* __restrict__ sums,
                                                const float* __restrict__ counts,
                                                float* __restrict__ out) {
    int i = blockIdx.x * 256 + threadIdx.x;
    if (i < N_GRAPHS * NF) out[i] = sums[i] / fmaxf(counts[i >> 7], 1.f);
}

// ----------------------------------------------------------------
extern "C" void kernel_launch(void* const* d_in, const int* in_sizes, int n_in,
                              void* d_out, int out_size, void* d_ws, size_t ws_size,
                              hipStream_t stream) {
    const float* x     = (const float*)d_in[0];
    const int*   ei    = (const int*)d_in[1];
    const int*   batch = (const int*)d_in[2];
    const float* W1 = (const float*)d_in[3];  const float* b1 = (const float*)d_in[4];
    const float* W2 = (const float*)d_in[5];  const float* b2 = (const float*)d_in[6];
    const float* W3 = (const float*)d_in[7];  const float* b3 = (const float*)d_in[8];
    const float* W4 = (const float*)d_in[9];  const float* b4 = (const float*)d_in[10];
    const int* src = ei;
    const int* dst = ei + N_EDGES;

    float* out   = (float*)d_out;
    float* h_out = out + N_GRAPHS * NF;            // 100000x128 fp32 (2nd output)

    // workspace (~85 MB)
    const size_t NE = (size_t)N_NODES * NF;        // 12.8M
    unsigned short* xb = (unsigned short*)d_ws;    // bf16 x
    unsigned short* t0 = xb + NE;                  // bf16 ping
    unsigned short* t1 = t0 + NE;                  // bf16 pong
    unsigned short* Wb = t1 + NE;                  // 4 x 128x128 bf16
    int*   rowptr = (int*)(Wb + 4 * NF * NF);      // N_NODES+1
    int*   deg    = rowptr + N_NODES + 1;          // N_NODES (also cursor)
    int*   bsum   = deg + N_NODES;                 // 128
    int*   csr    = bsum + 128;                    // N_EDGES
    float* sums   = (float*)(csr + N_EDGES);       // N_GRAPHS*NF
    float* cnts   = sums + N_GRAPHS * NF;          // N_GRAPHS

    const int edge_blocks   = N_EDGES / 256;       // 6250
    const int gather_blocks = N_NODES * 16 / 256;  // 6250
    const int gemm_blocks   = (N_NODES + 127) / 128; // 782

    hipMemsetAsync(deg, 0, N_NODES * sizeof(int), stream);
    hipMemsetAsync(sums, 0, (N_GRAPHS * NF + N_GRAPHS) * sizeof(float), stream);

    // ---- bf16 conversions
    conv_bf16<<<(int)(NE / 8 + 255) / 256, 256, 0, stream>>>((const float4*)x, (uint4*)xb, (int)(NE / 8));
    conv_bf16<<<8, 256, 0, stream>>>((const float4*)W1, (uint4*)(Wb + 0 * NF * NF), NF * NF / 8);
    conv_bf16<<<8, 256, 0, stream>>>((const float4*)W2, (uint4*)(Wb + 1 * NF * NF), NF * NF / 8);
    conv_bf16<<<8, 256, 0, stream>>>((const float4*)W3, (uint4*)(Wb + 2 * NF * NF), NF * NF / 8);
    conv_bf16<<<8, 256, 0, stream>>>((const float4*)W4, (uint4*)(Wb + 3 * NF * NF), NF * NF / 8);

    // ---- CSR build (shared by both aggregations)
    hist<<<edge_blocks, 256, 0, stream>>>(dst, deg);
    scan_local<<<NB_SCAN, 256, 0, stream>>>(deg, rowptr, bsum);
    scan_block<<<1, 128, 0, stream>>>(bsum, NB_SCAN);
    scan_add<<<(N_NODES + 256) / 256, 256, 0, stream>>>(rowptr, bsum);
    hipMemsetAsync(deg, 0, N_NODES * sizeof(int), stream);
    fill_csr<<<edge_blocks, 256, 0, stream>>>(src, dst, rowptr, deg, csr);

    // ---- layer group 1
    gather_agg_bf16<<<gather_blocks, 256, 0, stream>>>((const uint4*)xb, rowptr, csr, (uint4*)t0);
    gemm_mfma<false><<<gemm_blocks, 256, 0, stream>>>(t0, Wb + 0 * NF * NF, b1, t1, N_NODES);
    gemm_mfma<false><<<gemm_blocks, 256, 0, stream>>>(t1, Wb + 1 * NF * NF, b2, t0, N_NODES); // h1 -> t0

    // ---- layer group 2
    gather_agg_bf16<<<gather_blocks, 256, 0, stream>>>((const uint4*)t0, rowptr, csr, (uint4*)t1);
    gemm_mfma<false><<<gemm_blocks, 256, 0, stream>>>(t1, Wb + 2 * NF * NF, b3, t0, N_NODES);
    gemm_mfma<true ><<<gemm_blocks, 256, 0, stream>>>(t0, Wb + 3 * NF * NF, b4, h_out, N_NODES); // h -> out

    // ---- global mean pool
    pool_sum<<<(N_NODES + 255) / 256, 128, 0, stream>>>(h_out, batch, sums, cnts);
    pool_div<<<(N_GRAPHS * NF + 255) / 256, 256, 0, stream>>>(sums, cnts, out);
}

// Round 4
// 541.199 us; speedup vs baseline: 11.0177x; 1.1635x over previous
//
#include <hip/hip_runtime.h>

#define N_NODES  100000
#define N_EDGES  1600000
#define NF       128
#define N_GRAPHS 100
#define NB_SCAN  98          // ceil(100000 / 1024)

typedef __attribute__((ext_vector_type(8))) short bf16x8;
typedef __attribute__((ext_vector_type(4))) float f32x4;
typedef unsigned int uint32;

// ---------------------------------------------------------------- bf16 helpers (RNE)
__device__ __forceinline__ unsigned short f2bf(float f) {
    union { float f; uint32 u; } x; x.f = f;
    return (unsigned short)((x.u + 0x7fffu + ((x.u >> 16) & 1u)) >> 16);
}
__device__ __forceinline__ uint32 pack2bf(float a, float b) {
    union { float f; uint32 u; } x, y; x.f = a; y.f = b;
    uint32 lo = (x.u + 0x7fffu + ((x.u >> 16) & 1u)) >> 16;
    uint32 hi = (y.u + 0x7fffu + ((y.u >> 16) & 1u)) & 0xffff0000u;
    return lo | hi;
}

// ---------------------------------------------------------------- fp32 -> bf16 convert (8 elems/thread)
__global__ __launch_bounds__(256) void conv_bf16(const float4* __restrict__ in,
                                                 uint4* __restrict__ out, int n8) {
    int i = blockIdx.x * 256 + threadIdx.x;
    if (i >= n8) return;
    float4 a = in[i * 2], b = in[i * 2 + 1];
    uint4 o;
    o.x = pack2bf(a.x, a.y); o.y = pack2bf(a.z, a.w);
    o.z = pack2bf(b.x, b.y); o.w = pack2bf(b.z, b.w);
    out[i] = o;
}

// all 4 weight matrices in one launch: 4 x 128x128 / 8 = 8192 uint4
__global__ __launch_bounds__(256) void conv_w4(const float4* __restrict__ w1,
                                               const float4* __restrict__ w2,
                                               const float4* __restrict__ w3,
                                               const float4* __restrict__ w4,
                                               uint4* __restrict__ out) {
    int i = blockIdx.x * 256 + threadIdx.x;          // 0..8191
    int wi = i >> 11, li = i & 2047;                 // 2048 uint4 per matrix
    const float4* src = (wi == 0) ? w1 : (wi == 1) ? w2 : (wi == 2) ? w3 : w4;
    float4 a = src[li * 2], b = src[li * 2 + 1];
    uint4 o;
    o.x = pack2bf(a.x, a.y); o.y = pack2bf(a.z, a.w);
    o.z = pack2bf(b.x, b.y); o.w = pack2bf(b.z, b.w);
    out[i] = o;
}

// ---------------------------------------------------------------- CSR build
__global__ __launch_bounds__(256) void hist(const int* __restrict__ dst,
                                            int* __restrict__ deg) {
    int e = blockIdx.x * 256 + threadIdx.x;
    if (e < N_EDGES) atomicAdd(&deg[dst[e]], 1);
}

__global__ __launch_bounds__(256) void scan_local(const int* __restrict__ deg,
                                                  int* __restrict__ rowptr,
                                                  int* __restrict__ bsum) {
    __shared__ int s[256];
    int t = threadIdx.x;
    int base = blockIdx.x * 1024 + t * 4;
    int v[4], sum = 0;
    #pragma unroll
    for (int i = 0; i < 4; ++i) {
        v[i] = (base + i < N_NODES) ? deg[base + i] : 0;
        sum += v[i];
    }
    s[t] = sum;
    __syncthreads();
    for (int off = 1; off < 256; off <<= 1) {
        int x = (t >= off) ? s[t - off] : 0;
        __syncthreads();
        s[t] += x;
        __syncthreads();
    }
    int excl = s[t] - sum;
    #pragma unroll
    for (int i = 0; i < 4; ++i) {
        if (base + i < N_NODES) rowptr[base + i] = excl;
        excl += v[i];
    }
    if (t == 255) bsum[blockIdx.x] = s[255];
}

__global__ __launch_bounds__(128) void scan_block(int* __restrict__ bsum, int nb) {
    __shared__ int s[128];
    int t = threadIdx.x;
    int v = (t < nb) ? bsum[t] : 0;
    s[t] = v;
    __syncthreads();
    for (int off = 1; off < 128; off <<= 1) {
        int x = (t >= off) ? s[t - off] : 0;
        __syncthreads();
        s[t] += x;
        __syncthreads();
    }
    if (t < nb) bsum[t] = s[t] - v;
}

__global__ __launch_bounds__(256) void scan_add(int* __restrict__ rowptr,
                                                const int* __restrict__ bsum) {
    int i = blockIdx.x * 256 + threadIdx.x;
    if (i < N_NODES) rowptr[i] += bsum[i >> 10];
    if (i == 0) rowptr[N_NODES] = N_EDGES;
}

__global__ __launch_bounds__(256) void fill_csr(const int* __restrict__ src,
                                                const int* __restrict__ dst,
                                                const int* __restrict__ rowptr,
                                                int* __restrict__ cur,
                                                int* __restrict__ csr) {
    int e = blockIdx.x * 256 + threadIdx.x;
    if (e < N_EDGES) {
        int d = dst[e];
        int pos = rowptr[d] + atomicAdd(&cur[d], 1);
        csr[pos] = src[e];
    }
}

// ---------------------------------------------------------------- bf16 gather: out[n] = x[n] + sum x[csr[e]]
__global__ __launch_bounds__(256) void gather_agg_bf16(const uint4* __restrict__ x,
                                                       const int* __restrict__ rowptr,
                                                       const int* __restrict__ csr,
                                                       uint4* __restrict__ out) {
    int idx = blockIdx.x * 256 + threadIdx.x;
    int node = idx >> 4, c = idx & 15;
    int beg = rowptr[node], end = rowptr[node + 1];

    float acc[8];
    {
        uint4 v = x[node * 16 + c];
        uint32 u[4] = {v.x, v.y, v.z, v.w};
        #pragma unroll
        for (int i = 0; i < 4; ++i) {
            union { uint32 b; float f; } lo, hi;
            lo.b = u[i] << 16; hi.b = u[i] & 0xffff0000u;
            acc[2 * i] = lo.f; acc[2 * i + 1] = hi.f;
        }
    }
    for (int e = beg; e < end; ++e) {
        int s = csr[e];
        uint4 v = x[s * 16 + c];
        uint32 u[4] = {v.x, v.y, v.z, v.w};
        #pragma unroll
        for (int i = 0; i < 4; ++i) {
            union { uint32 b; float f; } lo, hi;
            lo.b = u[i] << 16; hi.b = u[i] & 0xffff0000u;
            acc[2 * i] += lo.f; acc[2 * i + 1] += hi.f;
        }
    }
    uint4 o;
    o.x = pack2bf(acc[0], acc[1]); o.y = pack2bf(acc[2], acc[3]);
    o.z = pack2bf(acc[4], acc[5]); o.w = pack2bf(acc[6], acc[7]);
    out[node * 16 + c] = o;
}

// ---------------------------------------------------------------- MFMA GEMM: C = relu(A @ W^T + bias)
template <bool F32OUT>
__global__ __launch_bounds__(256) void gemm_mfma(const unsigned short* __restrict__ A,
                                                 const unsigned short* __restrict__ W,
                                                 const float* __restrict__ bias,
                                                 void* __restrict__ Cout, int M) {
    __shared__ unsigned short As[128 * 136];
    __shared__ unsigned short Ws[128 * 136];
    __shared__ float bs[128];
    int tid  = threadIdx.x;
    int row0 = blockIdx.x * 128;

    #pragma unroll
    for (int it = 0; it < 8; ++it) {
        int li = it * 256 + tid;
        int r = li >> 4, s = li & 15;
        uint4 v = make_uint4(0u, 0u, 0u, 0u);
        if (row0 + r < M) v = *(const uint4*)(A + (size_t)(row0 + r) * NF + s * 8);
        *(uint4*)&As[r * 136 + s * 8] = v;
    }
    #pragma unroll
    for (int it = 0; it < 8; ++it) {
        int li = it * 256 + tid;
        int r = li >> 4, s = li & 15;
        *(uint4*)&Ws[r * 136 + s * 8] = *(const uint4*)(W + r * NF + s * 8);
    }
    if (tid < 128) bs[tid] = bias[tid];
    __syncthreads();

    int wv = tid >> 6;
    int l  = tid & 63;
    int lm = l & 15;
    int q  = l >> 4;

    f32x4 acc[2][8];
    #pragma unroll
    for (int i = 0; i < 2; ++i)
        #pragma unroll
        for (int j = 0; j < 8; ++j) acc[i][j] = (f32x4){0.f, 0.f, 0.f, 0.f};

    #pragma unroll
    for (int ks = 0; ks < 4; ++ks) {
        int ko = ks * 32 + q * 8;
        bf16x8 a0 = *(const bf16x8*)&As[(wv * 32 + lm) * 136 + ko];
        bf16x8 a1 = *(const bf16x8*)&As[(wv * 32 + 16 + lm) * 136 + ko];
        #pragma unroll
        for (int ct = 0; ct < 8; ++ct) {
            bf16x8 b = *(const bf16x8*)&Ws[(ct * 16 + lm) * 136 + ko];
            acc[0][ct] = __builtin_amdgcn_mfma_f32_16x16x32_bf16(a0, b, acc[0][ct], 0, 0, 0);
            acc[1][ct] = __builtin_amdgcn_mfma_f32_16x16x32_bf16(a1, b, acc[1][ct], 0, 0, 0);
        }
    }

    #pragma unroll
    for (int rt = 0; rt < 2; ++rt) {
        #pragma unroll
        for (int ct = 0; ct < 8; ++ct) {
            int col = ct * 16 + lm;
            float bv = bs[col];
            #pragma unroll
            for (int r = 0; r < 4; ++r) {
                int row = row0 + wv * 32 + rt * 16 + q * 4 + r;
                if (row < M) {
                    float v = fmaxf(acc[rt][ct][r] + bv, 0.f);
                    if (F32OUT) ((float*)Cout)[(size_t)row * NF + col] = v;
                    else ((unsigned short*)Cout)[(size_t)row * NF + col] = f2bf(v);
                }
            }
        }
    }
}

// ---------------------------------------------------------------- pooling v2 (batch sorted)
// 256 thr = 2 segments x 128 feats; block covers 128 nodes, each thread scans 64.
__global__ __launch_bounds__(256) void pool_sum2(const float* __restrict__ h,
                                                 const int* __restrict__ batch,
                                                 float* __restrict__ sums) {
    int t = threadIdx.x;
    int f = t & 127, seg = t >> 7;
    int n0 = blockIdx.x * 128 + seg * 64;
    if (n0 >= N_NODES) return;
    int n1 = min(n0 + 64, N_NODES);
    int cur = batch[n0];                  // broadcast
    float acc = 0.f;
    for (int n = n0; n < n1; ++n) {
        int g = batch[n];
        if (g != cur) {                   // wave-uniform (all lanes same seg)
            atomicAdd(&sums[cur * NF + f], acc);
            acc = 0.f; cur = g;
        }
        acc += h[(size_t)n * NF + f];
    }
    atomicAdd(&sums[cur * NF + f], acc);
}

// counts via binary search on the sorted batch array; then divide
__global__ __launch_bounds__(256) void pool_div2(const float* __restrict__ sums,
                                                 const int* __restrict__ batch,
                                                 float* __restrict__ out) {
    int i = blockIdx.x * 256 + threadIdx.x;
    if (i >= N_GRAPHS * NF) return;
    int g = i >> 7;
    int lo = 0, hi = N_NODES;             // lower_bound(g)
    while (lo < hi) { int m = (lo + hi) >> 1; if (batch[m] < g) lo = m + 1; else hi = m; }
    int lo2 = lo, hi2 = N_NODES;          // lower_bound(g+1), start from lo
    while (lo2 < hi2) { int m = (lo2 + hi2) >> 1; if (batch[m] < g + 1) lo2 = m + 1; else hi2 = m; }
    float cnt = (float)(lo2 - lo);
    out[i] = sums[i] / fmaxf(cnt, 1.f);
}

// ----------------------------------------------------------------
extern "C" void kernel_launch(void* const* d_in, const int* in_sizes, int n_in,
                              void* d_out, int out_size, void* d_ws, size_t ws_size,
                              hipStream_t stream) {
    const float* x     = (const float*)d_in[0];
    const int*   ei    = (const int*)d_in[1];
    const int*   batch = (const int*)d_in[2];
    const float* W1 = (const float*)d_in[3];  const float* b1 = (const float*)d_in[4];
    const float* W2 = (const float*)d_in[5];  const float* b2 = (const float*)d_in[6];
    const float* W3 = (const float*)d_in[7];  const float* b3 = (const float*)d_in[8];
    const float* W4 = (const float*)d_in[9];  const float* b4 = (const float*)d_in[10];
    const int* src = ei;
    const int* dst = ei + N_EDGES;

    float* out   = (float*)d_out;
    float* h_out = out + N_GRAPHS * NF;            // 100000x128 fp32 (2nd output)

    // workspace (~85 MB)
    const size_t NE = (size_t)N_NODES * NF;
    unsigned short* xb = (unsigned short*)d_ws;
    unsigned short* t0 = xb + NE;
    unsigned short* t1 = t0 + NE;
    unsigned short* Wb = t1 + NE;                  // 4 x 128x128 bf16 contiguous
    int*   rowptr = (int*)(Wb + 4 * NF * NF);
    int*   deg    = rowptr + N_NODES + 1;
    int*   bsum   = deg + N_NODES;
    int*   csr    = bsum + 128;
    float* sums   = (float*)(csr + N_EDGES);       // N_GRAPHS*NF

    const int edge_blocks   = N_EDGES / 256;
    const int gather_blocks = N_NODES * 16 / 256;
    const int gemm_blocks   = (N_NODES + 127) / 128;

    hipMemsetAsync(deg, 0, N_NODES * sizeof(int), stream);
    hipMemsetAsync(sums, 0, N_GRAPHS * NF * sizeof(float), stream);

    // ---- bf16 conversions (x + all 4 weights in 2 launches)
    conv_bf16<<<(int)(NE / 8 + 255) / 256, 256, 0, stream>>>((const float4*)x, (uint4*)xb, (int)(NE / 8));
    conv_w4<<<32, 256, 0, stream>>>((const float4*)W1, (const float4*)W2,
                                    (const float4*)W3, (const float4*)W4, (uint4*)Wb);

    // ---- CSR build
    hist<<<edge_blocks, 256, 0, stream>>>(dst, deg);
    scan_local<<<NB_SCAN, 256, 0, stream>>>(deg, rowptr, bsum);
    scan_block<<<1, 128, 0, stream>>>(bsum, NB_SCAN);
    scan_add<<<(N_NODES + 256) / 256, 256, 0, stream>>>(rowptr, bsum);
    hipMemsetAsync(deg, 0, N_NODES * sizeof(int), stream);
    fill_csr<<<edge_blocks, 256, 0, stream>>>(src, dst, rowptr, deg, csr);

    // ---- layer group 1
    gather_agg_bf16<<<gather_blocks, 256, 0, stream>>>((const uint4*)xb, rowptr, csr, (uint4*)t0);
    gemm_mfma<false><<<gemm_blocks, 256, 0, stream>>>(t0, Wb + 0 * NF * NF, b1, t1, N_NODES);
    gemm_mfma<false><<<gemm_blocks, 256, 0, stream>>>(t1, Wb + 1 * NF * NF, b2, t0, N_NODES);

    // ---- layer group 2
    gather_agg_bf16<<<gather_blocks, 256, 0, stream>>>((const uint4*)t0, rowptr, csr, (uint4*)t1);
    gemm_mfma<false><<<gemm_blocks, 256, 0, stream>>>(t1, Wb + 2 * NF * NF, b3, t0, N_NODES);
    gemm_mfma<true ><<<gemm_blocks, 256, 0, stream>>>(t0, Wb + 3 * NF * NF, b4, h_out, N_NODES);

    // ---- global mean pool
    pool_sum2<<<(N_NODES + 127) / 128, 256, 0, stream>>>(h_out, batch, sums);
    pool_div2<<<(N_GRAPHS * NF + 255) / 256, 256, 0, stream>>>(sums, batch, out);
}

// Round 5
// 428.431 us; speedup vs baseline: 13.9177x; 1.2632x over previous
//
#include <hip/hip_runtime.h>

#define N_NODES  100000
#define N_EDGES  1600000
#define NF       128
#define N_GRAPHS 100
#define NBKT     196         // ceil(100000 / 512) coarse buckets
#define BKT_SHIFT 9
#define EPB      4096        // edges per block in bucket passes
#define EB_GRID  391         // ceil(1600000 / 4096)

typedef __attribute__((ext_vector_type(8))) short bf16x8;
typedef __attribute__((ext_vector_type(4))) float f32x4;
typedef unsigned int uint32;

// ---------------------------------------------------------------- bf16 helpers (RNE)
__device__ __forceinline__ unsigned short f2bf(float f) {
    union { float f; uint32 u; } x; x.f = f;
    return (unsigned short)((x.u + 0x7fffu + ((x.u >> 16) & 1u)) >> 16);
}
__device__ __forceinline__ uint32 pack2bf(float a, float b) {
    union { float f; uint32 u; } x, y; x.f = a; y.f = b;
    uint32 lo = (x.u + 0x7fffu + ((x.u >> 16) & 1u)) >> 16;
    uint32 hi = (y.u + 0x7fffu + ((y.u >> 16) & 1u)) & 0xffff0000u;
    return lo | hi;
}

// ---------------------------------------------------------------- fp32 -> bf16
__global__ __launch_bounds__(256) void conv_bf16(const float4* __restrict__ in,
                                                 uint4* __restrict__ out, int n8) {
    int i = blockIdx.x * 256 + threadIdx.x;
    if (i >= n8) return;
    float4 a = in[i * 2], b = in[i * 2 + 1];
    uint4 o;
    o.x = pack2bf(a.x, a.y); o.y = pack2bf(a.z, a.w);
    o.z = pack2bf(b.x, b.y); o.w = pack2bf(b.z, b.w);
    out[i] = o;
}

__global__ __launch_bounds__(256) void conv_w4(const float4* __restrict__ w1,
                                               const float4* __restrict__ w2,
                                               const float4* __restrict__ w3,
                                               const float4* __restrict__ w4,
                                               uint4* __restrict__ out) {
    int i = blockIdx.x * 256 + threadIdx.x;          // 0..8191
    int wi = i >> 11, li = i & 2047;
    const float4* src = (wi == 0) ? w1 : (wi == 1) ? w2 : (wi == 2) ? w3 : w4;
    float4 a = src[li * 2], b = src[li * 2 + 1];
    uint4 o;
    o.x = pack2bf(a.x, a.y); o.y = pack2bf(a.z, a.w);
    o.z = pack2bf(b.x, b.y); o.w = pack2bf(b.z, b.w);
    out[i] = o;
}

// ---------------------------------------------------------------- CSR build v2: two-level counting sort
// Pass A1: coarse histogram over dst>>9 (LDS-staged, 196 global atomics/block)
__global__ __launch_bounds__(256) void bhist(const int* __restrict__ dst,
                                             int* __restrict__ gcnt) {
    __shared__ int h[NBKT];
    int t = threadIdx.x;
    if (t < NBKT) h[t] = 0;
    __syncthreads();
    int e0 = blockIdx.x * EPB;
    #pragma unroll
    for (int i = 0; i < 16; ++i) {
        int e = e0 + i * 256 + t;
        if (e < N_EDGES) atomicAdd(&h[dst[e] >> BKT_SHIFT], 1);
    }
    __syncthreads();
    if (t < NBKT) atomicAdd(&gcnt[t], h[t]);
}

// Pass A1b: exclusive scan of 196 bucket counts; init cursors; tail rowptr
__global__ __launch_bounds__(256) void bscan(const int* __restrict__ gcnt,
                                             int* __restrict__ bbase,
                                             int* __restrict__ cur,
                                             int* __restrict__ rowptr) {
    __shared__ int s[256];
    int t = threadIdx.x;
    int v = (t < NBKT) ? gcnt[t] : 0;
    s[t] = v;
    __syncthreads();
    for (int o = 1; o < 256; o <<= 1) {
        int x = (t >= o) ? s[t - o] : 0;
        __syncthreads();
        s[t] += x;
        __syncthreads();
    }
    if (t < NBKT) { int ex = s[t] - v; bbase[t] = ex; cur[t] = ex; }
    if (t == 0)  { bbase[NBKT] = N_EDGES; rowptr[N_NODES] = N_EDGES; }
}

// Pass A2: scatter edges into coarse buckets, packed (dstLocal<<17)|src.
// Per-block LDS histogram -> one global reservation per bucket -> contiguous runs.
__global__ __launch_bounds__(256) void bscatter(const int* __restrict__ src,
                                                const int* __restrict__ dst,
                                                int* __restrict__ cur,
                                                uint32* __restrict__ ebuf) {
    __shared__ int lh[NBKT], lbase[NBKT], lcur[NBKT];
    int t = threadIdx.x;
    if (t < NBKT) lh[t] = 0;
    __syncthreads();
    int e0 = blockIdx.x * EPB;
    int d[16];
    #pragma unroll
    for (int i = 0; i < 16; ++i) {
        int e = e0 + i * 256 + t;
        d[i] = -1;
        if (e < N_EDGES) { d[i] = dst[e]; atomicAdd(&lh[d[i] >> BKT_SHIFT], 1); }
    }
    __syncthreads();
    if (t < NBKT) { lbase[t] = atomicAdd(&cur[t], lh[t]); lcur[t] = 0; }
    __syncthreads();
    #pragma unroll
    for (int i = 0; i < 16; ++i) {
        int e = e0 + i * 256 + t;
        if (e < N_EDGES) {
            int b = d[i] >> BKT_SHIFT;
            int off = atomicAdd(&lcur[b], 1);
            ebuf[lbase[b] + off] = ((uint32)(d[i] & 511) << 17) | (uint32)src[e];
        }
    }
}

// Pass B: per-bucket fine counting sort (512 nodes). csr writes confined to a
// ~32KB L2-resident window -> no write amplification. Also emits rowptr.
__global__ __launch_bounds__(256) void bfine(const uint32* __restrict__ ebuf,
                                             const int* __restrict__ bbase,
                                             int* __restrict__ rowptr,
                                             int* __restrict__ csr) {
    __shared__ int deg[512];
    __shared__ int off[512];
    __shared__ int sc[256];
    int t = threadIdx.x;
    int bkt = blockIdx.x;
    int beg = bbase[bkt], end = bbase[bkt + 1];
    deg[t] = 0; deg[t + 256] = 0;
    __syncthreads();
    for (int e = beg + t; e < end; e += 256)
        atomicAdd(&deg[ebuf[e] >> 17], 1);
    __syncthreads();
    int d0 = deg[2 * t], d1 = deg[2 * t + 1];
    sc[t] = d0 + d1;
    __syncthreads();
    for (int o = 1; o < 256; o <<= 1) {
        int x = (t >= o) ? sc[t - o] : 0;
        __syncthreads();
        sc[t] += x;
        __syncthreads();
    }
    int ex = sc[t] - (d0 + d1);
    off[2 * t] = ex; off[2 * t + 1] = ex + d0;
    __syncthreads();
    int node0 = bkt << BKT_SHIFT;
    for (int i = t; i < 512; i += 256) {
        int node = node0 + i;
        if (node < N_NODES) rowptr[node] = beg + off[i];
    }
    __syncthreads();
    for (int e = beg + t; e < end; e += 256) {
        uint32 u = ebuf[e];
        int dl = u >> 17, s = (int)(u & 0x1FFFFu);
        int pos = atomicAdd(&off[dl], 1);
        csr[beg + pos] = s;
    }
}

// ---------------------------------------------------------------- bf16 gather: out[n] = x[n] + sum x[csr[e]]
__global__ __launch_bounds__(256) void gather_agg_bf16(const uint4* __restrict__ x,
                                                       const int* __restrict__ rowptr,
                                                       const int* __restrict__ csr,
                                                       uint4* __restrict__ out) {
    int idx = blockIdx.x * 256 + threadIdx.x;
    int node = idx >> 4, c = idx & 15;
    int beg = rowptr[node], end = rowptr[node + 1];

    float acc[8];
    {
        uint4 v = x[node * 16 + c];
        uint32 u[4] = {v.x, v.y, v.z, v.w};
        #pragma unroll
        for (int i = 0; i < 4; ++i) {
            union { uint32 b; float f; } lo, hi;
            lo.b = u[i] << 16; hi.b = u[i] & 0xffff0000u;
            acc[2 * i] = lo.f; acc[2 * i + 1] = hi.f;
        }
    }
    for (int e = beg; e < end; ++e) {
        int s = csr[e];
        uint4 v = x[s * 16 + c];
        uint32 u[4] = {v.x, v.y, v.z, v.w};
        #pragma unroll
        for (int i = 0; i < 4; ++i) {
            union { uint32 b; float f; } lo, hi;
            lo.b = u[i] << 16; hi.b = u[i] & 0xffff0000u;
            acc[2 * i] += lo.f; acc[2 * i + 1] += hi.f;
        }
    }
    uint4 o;
    o.x = pack2bf(acc[0], acc[1]); o.y = pack2bf(acc[2], acc[3]);
    o.z = pack2bf(acc[4], acc[5]); o.w = pack2bf(acc[6], acc[7]);
    out[node * 16 + c] = o;
}

// ---------------------------------------------------------------- fused MLP: C = relu(relu(A Wa^T + ba) Wb^T + bb)
// K=128 lives inside the 128-row block tile, so mid never leaves LDS.
template <bool F32OUT>
__global__ __launch_bounds__(256) void mlp_mfma(const unsigned short* __restrict__ A,
                                                const unsigned short* __restrict__ Wa,
                                                const float* __restrict__ ba,
                                                const unsigned short* __restrict__ Wb,
                                                const float* __restrict__ bb,
                                                void* __restrict__ Cout, int M) {
    __shared__ unsigned short As[128 * 136];   // A tile, then mid tile
    __shared__ unsigned short Ws[128 * 136];   // Wa, then Wb
    __shared__ float bs1[128], bs2[128];
    int tid  = threadIdx.x;
    int row0 = blockIdx.x * 128;

    #pragma unroll
    for (int it = 0; it < 8; ++it) {
        int li = it * 256 + tid;
        int r = li >> 4, s = li & 15;
        uint4 v = make_uint4(0u, 0u, 0u, 0u);
        if (row0 + r < M) v = *(const uint4*)(A + (size_t)(row0 + r) * NF + s * 8);
        *(uint4*)&As[r * 136 + s * 8] = v;
        *(uint4*)&Ws[r * 136 + s * 8] = *(const uint4*)(Wa + r * NF + s * 8);
    }
    if (tid < 128) { bs1[tid] = ba[tid]; bs2[tid] = bb[tid]; }
    __syncthreads();

    int wv = tid >> 6;          // wave -> rows wv*32..wv*32+31 (it owns mid + out for them)
    int l  = tid & 63;
    int lm = l & 15;
    int q  = l >> 4;

    f32x4 acc[2][8];
    #pragma unroll
    for (int i = 0; i < 2; ++i)
        #pragma unroll
        for (int j = 0; j < 8; ++j) acc[i][j] = (f32x4){0.f, 0.f, 0.f, 0.f};

    #pragma unroll
    for (int ks = 0; ks < 4; ++ks) {          // pass 1: mid = A @ Wa^T
        int ko = ks * 32 + q * 8;
        bf16x8 a0 = *(const bf16x8*)&As[(wv * 32 + lm) * 136 + ko];
        bf16x8 a1 = *(const bf16x8*)&As[(wv * 32 + 16 + lm) * 136 + ko];
        #pragma unroll
        for (int ct = 0; ct < 8; ++ct) {
            bf16x8 b = *(const bf16x8*)&Ws[(ct * 16 + lm) * 136 + ko];
            acc[0][ct] = __builtin_amdgcn_mfma_f32_16x16x32_bf16(a0, b, acc[0][ct], 0, 0, 0);
            acc[1][ct] = __builtin_amdgcn_mfma_f32_16x16x32_bf16(a1, b, acc[1][ct], 0, 0, 0);
        }
    }
    __syncthreads();            // all LDS reads of pass 1 done

    // mid -> As (bias+relu+bf16; C-layout scatter, 2-way bank alias = free); Wb -> Ws
    #pragma unroll
    for (int rt = 0; rt < 2; ++rt)
        #pragma unroll
        for (int ct = 0; ct < 8; ++ct) {
            int col = ct * 16 + lm;
            float bv = bs1[col];
            #pragma unroll
            for (int r = 0; r < 4; ++r) {
                int rr = wv * 32 + rt * 16 + q * 4 + r;
                As[rr * 136 + col] = f2bf(fmaxf(acc[rt][ct][r] + bv, 0.f));
            }
        }
    #pragma unroll
    for (int it = 0; it < 8; ++it) {
        int li = it * 256 + tid;
        int r = li >> 4, s = li & 15;
        *(uint4*)&Ws[r * 136 + s * 8] = *(const uint4*)(Wb + r * NF + s * 8);
    }
    __syncthreads();

    #pragma unroll
    for (int i = 0; i < 2; ++i)
        #pragma unroll
        for (int j = 0; j < 8; ++j) acc[i][j] = (f32x4){0.f, 0.f, 0.f, 0.f};

    #pragma unroll
    for (int ks = 0; ks < 4; ++ks) {          // pass 2: out = mid @ Wb^T
        int ko = ks * 32 + q * 8;
        bf16x8 a0 = *(const bf16x8*)&As[(wv * 32 + lm) * 136 + ko];
        bf16x8 a1 = *(const bf16x8*)&As[(wv * 32 + 16 + lm) * 136 + ko];
        #pragma unroll
        for (int ct = 0; ct < 8; ++ct) {
            bf16x8 b = *(const bf16x8*)&Ws[(ct * 16 + lm) * 136 + ko];
            acc[0][ct] = __builtin_amdgcn_mfma_f32_16x16x32_bf16(a0, b, acc[0][ct], 0, 0, 0);
            acc[1][ct] = __builtin_amdgcn_mfma_f32_16x16x32_bf16(a1, b, acc[1][ct], 0, 0, 0);
        }
    }

    #pragma unroll
    for (int rt = 0; rt < 2; ++rt)
        #pragma unroll
        for (int ct = 0; ct < 8; ++ct) {
            int col = ct * 16 + lm;
            float bv = bs2[col];
            #pragma unroll
            for (int r = 0; r < 4; ++r) {
                int row = row0 + wv * 32 + rt * 16 + q * 4 + r;
                if (row < M) {
                    float v = fmaxf(acc[rt][ct][r] + bv, 0.f);
                    if (F32OUT) ((float*)Cout)[(size_t)row * NF + col] = v;
                    else ((unsigned short*)Cout)[(size_t)row * NF + col] = f2bf(v);
                }
            }
        }
}

// ---------------------------------------------------------------- pooling (batch sorted)
__global__ __launch_bounds__(256) void pool_sum2(const float* __restrict__ h,
                                                 const int* __restrict__ batch,
                                                 float* __restrict__ sums) {
    int t = threadIdx.x;
    int f = t & 127, seg = t >> 7;
    int n0 = blockIdx.x * 128 + seg * 64;
    if (n0 >= N_NODES) return;
    int n1 = min(n0 + 64, N_NODES);
    int cur = batch[n0];
    float acc = 0.f;
    for (int n = n0; n < n1; ++n) {
        int g = batch[n];
        if (g != cur) {
            atomicAdd(&sums[cur * NF + f], acc);
            acc = 0.f; cur = g;
        }
        acc += h[(size_t)n * NF + f];
    }
    atomicAdd(&sums[cur * NF + f], acc);
}

__global__ __launch_bounds__(256) void pool_div2(const float* __restrict__ sums,
                                                 const int* __restrict__ batch,
                                                 float* __restrict__ out) {
    int i = blockIdx.x * 256 + threadIdx.x;
    if (i >= N_GRAPHS * NF) return;
    int g = i >> 7;
    int lo = 0, hi = N_NODES;
    while (lo < hi) { int m = (lo + hi) >> 1; if (batch[m] < g) lo = m + 1; else hi = m; }
    int lo2 = lo, hi2 = N_NODES;
    while (lo2 < hi2) { int m = (lo2 + hi2) >> 1; if (batch[m] < g + 1) lo2 = m + 1; else hi2 = m; }
    float cnt = (float)(lo2 - lo);
    out[i] = sums[i] / fmaxf(cnt, 1.f);
}

// ----------------------------------------------------------------
extern "C" void kernel_launch(void* const* d_in, const int* in_sizes, int n_in,
                              void* d_out, int out_size, void* d_ws, size_t ws_size,
                              hipStream_t stream) {
    const float* x     = (const float*)d_in[0];
    const int*   ei    = (const int*)d_in[1];
    const int*   batch = (const int*)d_in[2];
    const float* W1 = (const float*)d_in[3];  const float* b1 = (const float*)d_in[4];
    const float* W2 = (const float*)d_in[5];  const float* b2 = (const float*)d_in[6];
    const float* W3 = (const float*)d_in[7];  const float* b3 = (const float*)d_in[8];
    const float* W4 = (const float*)d_in[9];  const float* b4 = (const float*)d_in[10];
    const int* src = ei;
    const int* dst = ei + N_EDGES;

    float* out   = (float*)d_out;
    float* h_out = out + N_GRAPHS * NF;            // 100000x128 fp32 (2nd output)

    // workspace (~90 MB)
    const size_t NE = (size_t)N_NODES * NF;
    unsigned short* xb = (unsigned short*)d_ws;    // bf16 x
    unsigned short* t0 = xb + NE;
    unsigned short* t1 = t0 + NE;
    unsigned short* Wb = t1 + NE;                  // 4 x 128x128 bf16
    int*    rowptr = (int*)(Wb + 4 * NF * NF);     // N_NODES+1
    int*    csr    = rowptr + N_NODES + 1;         // N_EDGES
    uint32* ebuf   = (uint32*)(csr + N_EDGES);     // N_EDGES (coarse-bucketed packed)
    int*    gcnt   = (int*)(ebuf + N_EDGES);       // NBKT
    int*    bbase  = gcnt + NBKT;                  // NBKT+1
    int*    curp   = bbase + NBKT + 1;             // NBKT
    float*  sums   = (float*)(curp + NBKT);        // N_GRAPHS*NF

    const int gather_blocks = N_NODES * 16 / 256;  // 6250
    const int gemm_blocks   = (N_NODES + 127) / 128;

    hipMemsetAsync(gcnt, 0, NBKT * sizeof(int), stream);
    hipMemsetAsync(sums, 0, N_GRAPHS * NF * sizeof(float), stream);

    // ---- bf16 conversions
    conv_bf16<<<(int)(NE / 8 + 255) / 256, 256, 0, stream>>>((const float4*)x, (uint4*)xb, (int)(NE / 8));
    conv_w4<<<32, 256, 0, stream>>>((const float4*)W1, (const float4*)W2,
                                    (const float4*)W3, (const float4*)W4, (uint4*)Wb);

    // ---- CSR build v2 (two-level counting sort)
    bhist<<<EB_GRID, 256, 0, stream>>>(dst, gcnt);
    bscan<<<1, 256, 0, stream>>>(gcnt, bbase, curp, rowptr);
    bscatter<<<EB_GRID, 256, 0, stream>>>(src, dst, curp, ebuf);
    bfine<<<NBKT, 256, 0, stream>>>(ebuf, bbase, rowptr, csr);

    // ---- layer group 1: agg + fused MLP1
    gather_agg_bf16<<<gather_blocks, 256, 0, stream>>>((const uint4*)xb, rowptr, csr, (uint4*)t0);
    mlp_mfma<false><<<gemm_blocks, 256, 0, stream>>>(t0, Wb + 0 * NF * NF, b1,
                                                     Wb + 1 * NF * NF, b2, t1, N_NODES);

    // ---- layer group 2: agg + fused MLP2
    gather_agg_bf16<<<gather_blocks, 256, 0, stream>>>((const uint4*)t1, rowptr, csr, (uint4*)t0);
    mlp_mfma<true ><<<gemm_blocks, 256, 0, stream>>>(t0, Wb + 2 * NF * NF, b3,
                                                     Wb + 3 * NF * NF, b4, h_out, N_NODES);

    // ---- global mean pool
    pool_sum2<<<(N_NODES + 127) / 128, 256, 0, stream>>>(h_out, batch, sums);
    pool_div2<<<(N_GRAPHS * NF + 255) / 256, 256, 0, stream>>>(sums, batch, out);
}